// Round 8
// baseline (30.170 us; speedup 1.0000x reference)
//
#include <hip/hip_runtime.h>
#include <math.h>

#define CAP 128  // per-block record capacity; hits/block ~ Poisson(2), P(>128) ~ 0

// ---- K1: deg atomics + CE (block 0) + per-block (r,c,ss) compaction ------
__global__ __launch_bounds__(256) void k1_deg_ss_ce(
        const int* __restrict__ row, const int* __restrict__ col,
        const int* __restrict__ batch, unsigned int* __restrict__ deg,
        int4* __restrict__ recs, unsigned int* __restrict__ hcnt, int E, int D4,
        const float* __restrict__ x,
        const float* __restrict__ logits, const int* __restrict__ labels,
        double* __restrict__ ce_acc, int G, int C) {
    __shared__ unsigned int lcnt;
    if (threadIdx.x == 0) lcnt = 0u;
    __syncthreads();

    int e = blockIdx.x * blockDim.x + threadIdx.x;
    const int lane = threadIdx.x & 63;
    int r = 0, c = 0;
    bool hit = false;
    if (e < E) {
        r = row[e];
        c = col[e];
        if (batch[r] == batch[c]) {
            hit = true;
            atomicAdd(&deg[r], 1u);
        }
    }

    // wave-cooperative feature gather: ss = ||x_r - x_c||^2 for each hit lane
    float myss = 0.f;
    unsigned long long mask = __ballot(hit);
    while (mask) {
        int src = __ffsll((unsigned long long)mask) - 1;
        mask &= mask - 1;
        int rr = __shfl(r, src);
        int cc = __shfl(c, src);
        const float4 a = ((const float4*)(x + (size_t)rr * (size_t)(D4 * 4)))[lane];
        const float4 b = ((const float4*)(x + (size_t)cc * (size_t)(D4 * 4)))[lane];
        float dx = a.x - b.x, dy = a.y - b.y, dz = a.z - b.z, dw = a.w - b.w;
        float ss = dx * dx + dy * dy + dz * dz + dw * dw;
        #pragma unroll
        for (int o = 32; o > 0; o >>= 1) ss += __shfl_xor(ss, o);
        if (lane == src) myss = ss;
    }

    if (hit) {
        unsigned int idx = atomicAdd(&lcnt, 1u);   // LDS atomic: block-local
        if (idx < CAP) {
            int4 rec;
            rec.x = r; rec.y = c; rec.z = __float_as_int(myss); rec.w = 0;
            recs[(size_t)blockIdx.x * CAP + idx] = rec;
        }
    }
    __syncthreads();
    if (threadIdx.x == 0) hcnt[blockIdx.x] = (lcnt < CAP) ? lcnt : CAP;

    // CE rides along on block 0
    if (blockIdx.x == 0) {
        __shared__ float sh[128];
        int g = threadIdx.x;
        if (g < 128) {
            float lp = 0.f;
            if (g < G) {
                const float* lg = logits + (size_t)g * C;
                float m = lg[0];
                for (int d = 1; d < C; ++d) m = fmaxf(m, lg[d]);
                float s = 0.f;
                for (int d = 0; d < C; ++d) s += expf(lg[d] - m);
                lp = lg[labels[g]] - m - logf(s);
            }
            sh[g] = lp;
        }
        __syncthreads();
        for (int o = 64; o > 0; o >>= 1) {
            if (threadIdx.x < o) sh[threadIdx.x] += sh[threadIdx.x + o];
            __syncthreads();
        }
        if (threadIdx.x == 0) *ce_acc = -(double)sh[0] / (double)G;
    }
}

// ---- K2: single block — energy over records + finalize --------------------
__global__ __launch_bounds__(1024) void k2_energy_fin(
        const int4* __restrict__ recs, const unsigned int* __restrict__ hcnt,
        const unsigned int* __restrict__ deg, const double* __restrict__ ce_acc,
        const int* __restrict__ batch, int N, int nb, float* __restrict__ out) {
    double acc = 0.0;
    for (int b = threadIdx.x; b < nb; b += blockDim.x) {
        unsigned int n = hcnt[b];
        for (unsigned int s = 0; s < n; ++s) {
            int4 rec = recs[(size_t)b * CAP + s];
            unsigned int dr = deg[rec.x];
            unsigned int dc = deg[rec.y];
            if (dc == 0u) continue;  // dr >= 1 by construction
            float ss = __int_as_float(rec.z);
            float ir = 1.0f / sqrtf((float)dr);
            float ic = 1.0f / sqrtf((float)dc);
            acc += (double)((ir * ic) * ss);
        }
    }
    // block reduction: wave shfl + LDS
    #pragma unroll
    for (int o = 32; o > 0; o >>= 1) acc += __shfl_xor(acc, o);
    __shared__ double sd[16];
    int w = threadIdx.x >> 6;
    if ((threadIdx.x & 63) == 0) sd[w] = acc;
    __syncthreads();
    if (threadIdx.x == 0) {
        double t = 0.0;
        int nw = blockDim.x >> 6;
        for (int i = 0; i < nw; ++i) t += sd[i];
        double ng = (double)(batch[N - 1] + 1);
        out[0] = (float)(*ce_acc + t / ng);
    }
}

extern "C" void kernel_launch(void* const* d_in, const int* in_sizes, int n_in,
                              void* d_out, int out_size, void* d_ws, size_t ws_size,
                              hipStream_t stream) {
    const float* logits = (const float*)d_in[0];
    const int* labels = (const int*)d_in[1];
    const float* x = (const float*)d_in[2];
    const int* edge_index = (const int*)d_in[3];
    const int* batch = (const int*)d_in[4];

    const int C = 10;
    const int G = in_sizes[0] / C;            // 128
    const int E = in_sizes[3] / 2;            // 320000
    const int N = in_sizes[4];                // 100000
    const int D = in_sizes[2] / N;            // 256
    const int D4 = D / 4;

    const int* row = edge_index;
    const int* col = edge_index + E;

    int nb = (E + 255) / 256;                 // 1250

    // workspace: deg[N] | ce_acc | hcnt[nb] | pad | recs[nb*CAP]
    size_t off = 0;
    unsigned int* deg = (unsigned int*)((char*)d_ws + off); off += (size_t)N * 4;
    off = (off + 15) & ~(size_t)15;
    double* ce_acc = (double*)((char*)d_ws + off);          off += 16;
    unsigned int* hcnt = (unsigned int*)((char*)d_ws + off); off += (size_t)nb * 4;
    off = (off + 15) & ~(size_t)15;
    int4* recs = (int4*)((char*)d_ws + off);

    float* out = (float*)d_out;

    hipMemsetAsync(deg, 0, (size_t)N * 4, stream);

    k1_deg_ss_ce<<<nb, 256, 0, stream>>>(row, col, batch, deg, recs, hcnt,
                                         E, D4, x, logits, labels, ce_acc, G, C);

    k2_energy_fin<<<1, 1024, 0, stream>>>(recs, hcnt, deg, ce_acc,
                                          batch, N, nb, out);
}

// Round 9
// 20.456 us; speedup vs baseline: 1.4748x; 1.4748x over previous
//
#include <hip/hip_runtime.h>
#include <math.h>

// ---- K1: deg atomics (thread/edge); block 0 computes CE -> out[0] --------
__global__ __launch_bounds__(256) void deg_ce_kernel(
        const int* __restrict__ row, const int* __restrict__ col,
        const int* __restrict__ batch, unsigned int* __restrict__ deg, int E,
        const float* __restrict__ logits, const int* __restrict__ labels,
        float* __restrict__ out, int G, int C) {
    int e = blockIdx.x * blockDim.x + threadIdx.x;
    if (e < E) {
        int r = row[e], c = col[e];
        if (batch[r] == batch[c]) atomicAdd(&deg[r], 1u);
    }
    if (blockIdx.x == 0) {
        __shared__ float sh[128];
        int g = threadIdx.x;
        if (g < 128) {
            float lp = 0.f;
            if (g < G) {
                const float* lg = logits + (size_t)g * C;
                float m = lg[0];
                for (int d = 1; d < C; ++d) m = fmaxf(m, lg[d]);
                float s = 0.f;
                for (int d = 0; d < C; ++d) s += expf(lg[d] - m);
                lp = lg[labels[g]] - m - logf(s);
            }
            sh[g] = lp;
        }
        __syncthreads();
        for (int o = 64; o > 0; o >>= 1) {
            if (threadIdx.x < o) sh[threadIdx.x] += sh[threadIdx.x + o];
            __syncthreads();
        }
        // out[0] starts each call as ce; K2 (next kernel node) adds energy.
        if (threadIdx.x == 0) out[0] = (float)(-(double)sh[0] / (double)G);
    }
}

// ---- K2: energy (wave per 64-edge chunk), adds straight into out[0] ------
__global__ __launch_bounds__(256) void energy_kernel(
        const float* __restrict__ x,
        const int* __restrict__ row, const int* __restrict__ col,
        const int* __restrict__ batch, const unsigned int* __restrict__ deg,
        float* __restrict__ out, int E, int D4, int N) {
    int gtid = blockIdx.x * blockDim.x + threadIdx.x;
    int wave = gtid >> 6;
    int lane = threadIdx.x & 63;
    int wv = threadIdx.x >> 6;

    int e = wave * 64 + lane;
    int r = 0, c = 0;
    float norm = 0.f;
    bool hit = false;
    if (e < E) {
        r = row[e];
        c = col[e];
        if (batch[r] == batch[c]) {
            unsigned int dr = deg[r], dc = deg[c];
            if (dr > 0 && dc > 0) {
                float ir = 1.0f / sqrtf((float)dr);
                float ic = 1.0f / sqrtf((float)dc);
                norm = ir * ic;
                hit = true;
            }
        }
    }

    double wsum = 0.0;
    unsigned long long mask = __ballot(hit);
    while (mask) {
        int src = __ffsll((unsigned long long)mask) - 1;
        mask &= mask - 1;
        int rr = __shfl(r, src);
        int cc = __shfl(c, src);
        float nn = __shfl(norm, src);
        const float4 a = ((const float4*)(x + (size_t)rr * (size_t)(D4 * 4)))[lane];
        const float4 b = ((const float4*)(x + (size_t)cc * (size_t)(D4 * 4)))[lane];
        float dx = a.x - b.x, dy = a.y - b.y, dz = a.z - b.z, dw = a.w - b.w;
        float ss = dx * dx + dy * dy + dz * dz + dw * dw;
        #pragma unroll
        for (int o = 32; o > 0; o >>= 1) ss += __shfl_xor(ss, o);
        if (lane == 0) wsum += (double)(nn * ss);
    }

    // block-level reduction of the 4 wave sums -> 1 float atomic per block
    __shared__ double sdw[4];
    if (lane == 0) sdw[wv] = wsum;
    __syncthreads();
    if (threadIdx.x == 0) {
        double bsum = sdw[0] + sdw[1] + sdw[2] + sdw[3];
        if (bsum != 0.0) {
            double ng = (double)(batch[N - 1] + 1);
            atomicAdd(out, (float)(bsum / ng));
        }
    }
}

extern "C" void kernel_launch(void* const* d_in, const int* in_sizes, int n_in,
                              void* d_out, int out_size, void* d_ws, size_t ws_size,
                              hipStream_t stream) {
    const float* logits = (const float*)d_in[0];
    const int* labels = (const int*)d_in[1];
    const float* x = (const float*)d_in[2];
    const int* edge_index = (const int*)d_in[3];
    const int* batch = (const int*)d_in[4];

    const int C = 10;
    const int G = in_sizes[0] / C;            // 128
    const int E = in_sizes[3] / 2;            // 320000
    const int N = in_sizes[4];                // 100000
    const int D = in_sizes[2] / N;            // 256
    const int D4 = D / 4;

    const int* row = edge_index;
    const int* col = edge_index + E;

    unsigned int* deg = (unsigned int*)d_ws;
    float* out = (float*)d_out;

    hipMemsetAsync(deg, 0, (size_t)N * 4, stream);

    int degBlocks = (E + 255) / 256;
    deg_ce_kernel<<<degBlocks, 256, 0, stream>>>(row, col, batch, deg, E,
                                                 logits, labels, out, G, C);

    int waves = (E + 63) / 64;
    int eBlocks = (waves + 3) / 4;            // 4 waves per 256-thread block
    energy_kernel<<<eBlocks, 256, 0, stream>>>(x, row, col, batch, deg,
                                               out, E, D4, N);
}